// Round 4
// baseline (482.611 us; speedup 1.0000x reference)
//
#include <hip/hip_runtime.h>
#include <hip/hip_bf16.h>

// Problem: B=2, C=64, H=W=96 -> M=N=9216
//   scores[b,m,n] = sum_c yi[b,c,m]*pi[b,c,n] ; weight = softmax over m
//   out[b,c,n]    = sum_m yi[b,c,m]*weight[b,m,n]
// == flash attention with Q=pi (queries n), K=V=yi (keys m), head dim 64.
//
// R4: R3's dbuf cost 72KB LDS -> 2 blocks/CU (occupancy 17%) and S=16 wrote
// 132MB of partials. This round: single-buffered K/V (48KB -> 3 blocks/CU,
// 18 waves), staging still pure global_load_lds from prepacked global
// (2 barriers/tile; stage stall covered by 3-block TLP), S=8 (768 blocks =
// 3/CU uniform, 66MB partials), T13 defer-rescale, T5 setprio, reduce x4.

#define CC 64
#define MM 9216
#define BB 2
#define WAVES 6
#define NPW 32                 // query columns per wave
#define NBLK (WAVES * NPW)     // 192
#define NBX (MM / NBLK)        // 48
#define MTILE 64
#define NT (MM / MTILE)        // 144

typedef __bf16 bf16x8 __attribute__((ext_vector_type(8)));
typedef __bf16 bf16x4 __attribute__((ext_vector_type(4)));
typedef float f32x4 __attribute__((ext_vector_type(4)));

// row-XOR swizzle on 8-element groups (verified R2/R3)
__device__ __forceinline__ int swz(int r) { return ((r >> 1) ^ (r >> 4)) & 7; }

__device__ __forceinline__ void gld16(const void* gsrc, void* ldst) {
    __builtin_amdgcn_global_load_lds(
        (const __attribute__((address_space(1))) void*)gsrc,
        (__attribute__((address_space(3))) void*)ldst, 16, 0, 0);
}

// ---------------- prepass: bake conversion + transpose + swizzle (verified R3) ----
// kt_hi/kt_lo[b][m][c ^ (swz(m&63)<<3)]  (m-major: one 8KB contiguous block/tile)
// vt[b][c][t*64 + ((m&63) ^ (swz(c)<<3))]
__global__ __launch_bounds__(256)
void prepass(const float* __restrict__ yi, __bf16* __restrict__ kt_hi,
             __bf16* __restrict__ kt_lo, __bf16* __restrict__ vt)
{
    const int t = blockIdx.x;     // key tile 0..143
    const int b = blockIdx.y;
    const int tid = threadIdx.x;  // 256
    const float* src = yi + (size_t)b * CC * MM;

    for (int tsk = tid; tsk < 512; tsk += 256) {
        const int m = tsk & 63, g = tsk >> 6;
        const int m_abs = t * 64 + m;
        bf16x8 hh, ll;
        #pragma unroll
        for (int j = 0; j < 8; ++j) {
            const float f = src[(size_t)(g * 8 + j) * MM + m_abs];
            const __bf16 hi = (__bf16)f;
            hh[j] = hi;
            ll[j] = (__bf16)(f - (float)hi);
        }
        const size_t o = (size_t)(b * MM + m_abs) * 64 + ((g ^ swz(m)) << 3);
        *reinterpret_cast<bf16x8*>(kt_hi + o) = hh;
        *reinterpret_cast<bf16x8*>(kt_lo + o) = ll;
    }
    for (int tsk = tid; tsk < 512; tsk += 256) {
        const int c = tsk & 63, gm = tsk >> 6;
        const float* p = src + (size_t)c * MM + t * 64 + gm * 8;
        bf16x8 hh;
        #pragma unroll
        for (int j = 0; j < 8; ++j) hh[j] = (__bf16)p[j];
        *reinterpret_cast<bf16x8*>(
            vt + (size_t)(b * CC + c) * MM + t * 64 + ((gm ^ swz(c)) << 3)) = hh;
    }
}

// ---------------- main flash kernel ----------------
template<bool FINAL>
__global__ __launch_bounds__(WAVES * 64, 5)   // VGPR cap ~102: 18 waves/CU packs 5,5,4,4 per SIMD
void attn_main(const __bf16* __restrict__ kt_hi, const __bf16* __restrict__ kt_lo,
               const __bf16* __restrict__ vt, const float* __restrict__ pi,
               float* __restrict__ out, float* __restrict__ opart,
               float* __restrict__ mlpart, const int nsplits)
{
    __shared__ __align__(16) __bf16 k_hi[MTILE][64];       // 8KB (single-buffered)
    __shared__ __align__(16) __bf16 k_lo[MTILE][64];       // 8KB
    __shared__ __align__(16) __bf16 v_sm[CC][64];          // 8KB
    __shared__ __align__(16) __bf16 p_sm[WAVES][2][16][64]; // 24KB (both halves live)

    const int tid  = threadIdx.x;
    const int lane = tid & 63;
    const int wave = tid >> 6;     // 0..5
    const int ln   = lane & 15;
    const int lg   = lane >> 4;    // 0..3

    const int b     = blockIdx.z;
    const int split = blockIdx.y;
    const int tpb   = NT / nsplits;
    const int t0s   = split * tpb;
    const int n0    = blockIdx.x * NBLK + wave * NPW;   // this wave's 32 columns

    // ---- Q fragments (hi/lo split), 2 halves, loaded once (verified R3) ----
    bf16x8 qh[2][2], ql[2][2];
    #pragma unroll
    for (int h = 0; h < 2; ++h) {
        const float* qb = pi + (size_t)b * CC * MM + n0 + h * 16 + ln;
        #pragma unroll
        for (int ks = 0; ks < 2; ++ks)
            #pragma unroll
            for (int j = 0; j < 8; ++j) {
                const float f = qb[(size_t)(ks * 32 + lg * 8 + j) * MM];
                const __bf16 hi = (__bf16)f;
                qh[h][ks][j] = hi;
                ql[h][ks][j] = (__bf16)(f - (float)hi);
            }
    }

    f32x4 o[2][4];
    #pragma unroll
    for (int h = 0; h < 2; ++h)
        #pragma unroll
        for (int ct = 0; ct < 4; ++ct) o[h][ct] = (f32x4){0.f, 0.f, 0.f, 0.f};
    float run_max[2] = {-INFINITY, -INFINITY};
    float run_l[2]   = {0.f, 0.f};

    // ---- async staging: 24 x 1KB chunks, 4 per wave, linear LDS dest ----
    auto stage = [&](int t) {
        const size_t kbase = (size_t)(b * MM + t * 64) * 64;   // elements
        #pragma unroll
        for (int q = 0; q < 4; ++q) {
            const int ch = wave * 4 + q;        // wave-uniform
            if (ch < 8) {
                gld16(kt_hi + kbase + ch * 512 + lane * 8,
                      (char*)(&k_hi[0][0]) + ch * 1024);
            } else if (ch < 16) {
                const int j = ch - 8;
                gld16(kt_lo + kbase + j * 512 + lane * 8,
                      (char*)(&k_lo[0][0]) + j * 1024);
            } else {
                const int j = ch - 16;
                const int c = j * 8 + (lane >> 3);
                gld16(vt + (size_t)(b * CC + c) * MM + t * 64 + (lane & 7) * 8,
                      (char*)(&v_sm[0][0]) + j * 1024);
            }
        }
    };

    stage(t0s);
    __syncthreads();   // vmcnt drained -> tile 0 ready

    for (int it = 0; it < tpb; ++it) {
        // ---- QK^T: K-frag read once, used by both halves ----
        f32x4 s[2][4];
        #pragma unroll
        for (int h = 0; h < 2; ++h)
            #pragma unroll
            for (int mt = 0; mt < 4; ++mt) s[h][mt] = (f32x4){0.f, 0.f, 0.f, 0.f};
        __builtin_amdgcn_s_setprio(1);
        #pragma unroll
        for (int ks = 0; ks < 2; ++ks) {
            #pragma unroll
            for (int mt = 0; mt < 4; ++mt) {
                const int col = (ks * 32 + lg * 8) ^ (((ln >> 1) ^ mt) << 3);
                const bf16x8 ah = *reinterpret_cast<const bf16x8*>(&k_hi[mt * 16 + ln][col]);
                const bf16x8 al = *reinterpret_cast<const bf16x8*>(&k_lo[mt * 16 + ln][col]);
                #pragma unroll
                for (int h = 0; h < 2; ++h) {
                    s[h][mt] = __builtin_amdgcn_mfma_f32_16x16x32_bf16(ah, qh[h][ks], s[h][mt], 0, 0, 0);
                    s[h][mt] = __builtin_amdgcn_mfma_f32_16x16x32_bf16(ah, ql[h][ks], s[h][mt], 0, 0, 0);
                    s[h][mt] = __builtin_amdgcn_mfma_f32_16x16x32_bf16(al, qh[h][ks], s[h][mt], 0, 0, 0);
                }
            }
        }
        __builtin_amdgcn_s_setprio(0);

        // ---- online softmax per half (T13 defer-rescale, THR=8) ----
        #pragma unroll
        for (int h = 0; h < 2; ++h) {
            float tmax = -INFINITY;
            #pragma unroll
            for (int mt = 0; mt < 4; ++mt)
                #pragma unroll
                for (int r = 0; r < 4; ++r) tmax = fmaxf(tmax, s[h][mt][r]);
            tmax = fmaxf(tmax, __shfl_xor(tmax, 16));
            tmax = fmaxf(tmax, __shfl_xor(tmax, 32));

            float mnew = run_max[h];
            if (!__all(tmax - run_max[h] <= 8.f)) {   // wave-uniform branch
                mnew = fmaxf(run_max[h], tmax);
                const float corr = __expf(run_max[h] - mnew);  // 0 on first iter
                run_l[h] *= corr;
                #pragma unroll
                for (int ct = 0; ct < 4; ++ct) o[h][ct] *= corr;
                run_max[h] = mnew;
            }
            // P = exp(s - mnew), bounded by e^8 when deferred; bf16 handles it.
            float psum = 0.f;
            #pragma unroll
            for (int mt = 0; mt < 4; ++mt) {
                bf16x4 pp;
                #pragma unroll
                for (int r = 0; r < 4; ++r) {
                    const float pv = __expf(s[h][mt][r] - mnew);
                    psum += pv;
                    pp[r] = (__bf16)pv;
                }
                *reinterpret_cast<bf16x4*>(
                    &p_sm[wave][h][ln][(mt * 16 + lg * 4) ^ ((ln >> 1) << 3)]) = pp;
            }
            psum += __shfl_xor(psum, 16);
            psum += __shfl_xor(psum, 32);
            run_l[h] += psum;
        }

        // ---- PV: V-frag read ONCE, feeds both halves ----
        // same-wave LDS write->read on p_sm: in-order, no barrier needed
        __builtin_amdgcn_s_setprio(1);
        #pragma unroll
        for (int ks = 0; ks < 2; ++ks) {
            const int pcol = (ks * 32 + lg * 8) ^ ((ln >> 1) << 3);
            const bf16x8 bp0 = *reinterpret_cast<const bf16x8*>(&p_sm[wave][0][ln][pcol]);
            const bf16x8 bp1 = *reinterpret_cast<const bf16x8*>(&p_sm[wave][1][ln][pcol]);
            #pragma unroll
            for (int ct = 0; ct < 4; ++ct) {
                const int col = (ks * 32 + lg * 8) ^ (((ln >> 1) ^ ct) << 3);
                const bf16x8 av = *reinterpret_cast<const bf16x8*>(&v_sm[ct * 16 + ln][col]);
                o[0][ct] = __builtin_amdgcn_mfma_f32_16x16x32_bf16(av, bp0, o[0][ct], 0, 0, 0);
                o[1][ct] = __builtin_amdgcn_mfma_f32_16x16x32_bf16(av, bp1, o[1][ct], 0, 0, 0);
            }
        }
        __builtin_amdgcn_s_setprio(0);

        __syncthreads();   // all waves done reading k/v -> safe to overwrite
        if (it + 1 < tpb) stage(t0s + it + 1);
        __syncthreads();   // vmcnt drained -> next tile visible
    }

    // ---- epilogue ----
    #pragma unroll
    for (int h = 0; h < 2; ++h) {
        const int n_g = n0 + h * 16 + ln;
        if (FINAL) {
            const float inv = 1.f / run_l[h];
            #pragma unroll
            for (int ct = 0; ct < 4; ++ct)
                #pragma unroll
                for (int r = 0; r < 4; ++r) {
                    const int c = ct * 16 + lg * 4 + r;
                    out[((size_t)b * CC + c) * MM + n_g] = o[h][ct][r] * inv;
                }
        } else {
            const size_t pbase = (size_t)(b * nsplits + split) * CC * MM;
            #pragma unroll
            for (int ct = 0; ct < 4; ++ct)
                #pragma unroll
                for (int r = 0; r < 4; ++r) {
                    const int c = ct * 16 + lg * 4 + r;
                    opart[pbase + (size_t)c * MM + n_g] = o[h][ct][r];
                }
            if (lg == 0) {
                const size_t mb = ((size_t)(b * nsplits + split) * MM + n_g) * 2;
                mlpart[mb]     = run_max[h];
                mlpart[mb + 1] = run_l[h];
            }
        }
    }
}

// out = sum_s O_s * e^{m_s - M} / sum_s l_s * e^{m_s - M}  (4 n per thread)
template<int S>
__global__ __launch_bounds__(256)
void attn_reduce4(const float* __restrict__ opart, const float* __restrict__ mlpart,
                  float* __restrict__ out)
{
    const int t = blockIdx.x * 256 + threadIdx.x;
    if (t >= BB * CC * MM / 4) return;
    const int n  = (t * 4) % MM;
    const int bc = (t * 4) / MM;
    const int b  = bc / CC;
    const int c  = bc - b * CC;

    float wm[S][4], ls[S][4];
    float Mx[4] = {-INFINITY, -INFINITY, -INFINITY, -INFINITY};
    #pragma unroll
    for (int s = 0; s < S; ++s) {
        const float* mp = mlpart + ((size_t)(b * S + s) * MM + n) * 2;
        const float4 a = *reinterpret_cast<const float4*>(mp);
        const float4 q = *reinterpret_cast<const float4*>(mp + 4);
        wm[s][0] = a.x; ls[s][0] = a.y;
        wm[s][1] = a.z; ls[s][1] = a.w;
        wm[s][2] = q.x; ls[s][2] = q.y;
        wm[s][3] = q.z; ls[s][3] = q.w;
        #pragma unroll
        for (int j = 0; j < 4; ++j) Mx[j] = fmaxf(Mx[j], wm[s][j]);
    }
    float L[4] = {0.f, 0.f, 0.f, 0.f};
    #pragma unroll
    for (int s = 0; s < S; ++s)
        #pragma unroll
        for (int j = 0; j < 4; ++j) {
            wm[s][j] = __expf(wm[s][j] - Mx[j]);
            L[j] += ls[s][j] * wm[s][j];
        }
    float acc[4] = {0.f, 0.f, 0.f, 0.f};
    #pragma unroll
    for (int s = 0; s < S; ++s) {
        const float4 o4 = *reinterpret_cast<const float4*>(
            &opart[((size_t)(b * S + s) * CC + c) * MM + n]);
        acc[0] += o4.x * wm[s][0];
        acc[1] += o4.y * wm[s][1];
        acc[2] += o4.z * wm[s][2];
        acc[3] += o4.w * wm[s][3];
    }
    float4 r;
    r.x = acc[0] / L[0]; r.y = acc[1] / L[1];
    r.z = acc[2] / L[2]; r.w = acc[3] / L[3];
    *reinterpret_cast<float4*>(&out[(size_t)t * 4]) = r;
}

extern "C" void kernel_launch(void* const* d_in, const int* in_sizes, int n_in,
                              void* d_out, int out_size, void* d_ws, size_t ws_size,
                              hipStream_t stream) {
    const float* yi = (const float*)d_in[0];   // feature_yi (K = V)
    const float* pi = (const float*)d_in[1];   // feature_pi (Q)
    float* out = (float*)d_out;

    const size_t kelems = (size_t)BB * MM * 64;              // kt_hi / kt_lo elements
    const size_t velems = (size_t)BB * CC * MM;              // vt elements
    const size_t preB   = (kelems * 2 + velems) * 2;         // ~7.1 MB
    auto need = [&](int s) -> size_t {
        return preB + (size_t)BB * s * CC * MM * 4 + (size_t)BB * s * MM * 8;
    };

    int S = 1;
    if (d_ws) {
        if (ws_size >= need(8))      S = 8;   // 768 blocks = 3/CU uniform
        else if (ws_size >= need(4)) S = 4;
        else if (ws_size >= need(2)) S = 2;
    }
    if (S == 1) return;  // harness ws comfortably exceeds need(2) (R3 ran S=16)

    __bf16* kt_hi = (__bf16*)d_ws;
    __bf16* kt_lo = kt_hi + kelems;
    __bf16* vt    = kt_lo + kelems;
    float* opart  = (float*)(vt + velems);
    float* ml     = opart + (size_t)BB * S * CC * MM;

    prepass<<<dim3(NT, BB), dim3(256), 0, stream>>>(yi, kt_hi, kt_lo, vt);

    attn_main<false><<<dim3(NBX, S, BB), dim3(WAVES * 64), 0, stream>>>(
        kt_hi, kt_lo, vt, pi, out, opart, ml, S);

    const int total4 = BB * CC * MM / 4;
    const dim3 rg((total4 + 255) / 256), rb(256);
    if (S == 8)      attn_reduce4<8><<<rg, rb, 0, stream>>>(opart, ml, out);
    else if (S == 4) attn_reduce4<4><<<rg, rb, 0, stream>>>(opart, ml, out);
    else             attn_reduce4<2><<<rg, rb, 0, stream>>>(opart, ml, out);
}

// Round 5
// 158.700 us; speedup vs baseline: 3.0410x; 3.0410x over previous
//
#include <hip/hip_runtime.h>
#include <hip/hip_bf16.h>

// Problem: B=2, C=64, H=W=96 -> M=N=9216
//   scores[b,m,n] = sum_c yi[b,c,m]*pi[b,c,n] ; weight = softmax over m
//   out[b,c,n]    = sum_m yi[b,c,m]*weight[b,m,n]
// == flash attention with Q=pi (queries n), K=V=yi (keys m), head dim 64.
//
// R5: R4's 483us regression was a forced register spill (__launch_bounds__
// min-waves=5 capped the unified VGPR file at ~102 < ~150 needed; VGPR_Count
// 48 + FETCH_SIZE 524MB ~= scratch traffic). This round removes the cap and
// gets concurrency structurally: WAVES=3 x NPW=32 -> 36KB LDS -> 4 resident
// blocks/CU (4 independent barrier domains, 12 waves/CU). Single-buffered
// K/V staged via pure global_load_lds from prepacked swizzled global; the
// serial stage+drain of one block hides under the other 3 blocks' compute.
// S=8 splits (1536 blocks, 66MB partials). T13 defer-rescale, T5 setprio.

#define CC 64
#define MM 9216
#define BB 2
#define WAVES 3
#define NPW 32                 // query columns per wave
#define NBLK (WAVES * NPW)     // 96
#define NBX (MM / NBLK)        // 96
#define MTILE 64
#define NT (MM / MTILE)        // 144

typedef __bf16 bf16x8 __attribute__((ext_vector_type(8)));
typedef __bf16 bf16x4 __attribute__((ext_vector_type(4)));
typedef float f32x4 __attribute__((ext_vector_type(4)));

// row-XOR swizzle on 8-element groups (verified R2/R3/R4)
__device__ __forceinline__ int swz(int r) { return ((r >> 1) ^ (r >> 4)) & 7; }

__device__ __forceinline__ void gld16(const void* gsrc, void* ldst) {
    __builtin_amdgcn_global_load_lds(
        (const __attribute__((address_space(1))) void*)gsrc,
        (__attribute__((address_space(3))) void*)ldst, 16, 0, 0);
}

// ---------------- prepass: bake conversion + transpose + swizzle (verified R3) ----
// kt_hi/kt_lo[b][m][c ^ (swz(m&63)<<3)]  (m-major: one 8KB contiguous block/tile)
// vt[b][c][t*64 + ((m&63) ^ (swz(c)<<3))]
__global__ __launch_bounds__(256)
void prepass(const float* __restrict__ yi, __bf16* __restrict__ kt_hi,
             __bf16* __restrict__ kt_lo, __bf16* __restrict__ vt)
{
    const int t = blockIdx.x;     // key tile 0..143
    const int b = blockIdx.y;
    const int tid = threadIdx.x;  // 256
    const float* src = yi + (size_t)b * CC * MM;

    for (int tsk = tid; tsk < 512; tsk += 256) {
        const int m = tsk & 63, g = tsk >> 6;
        const int m_abs = t * 64 + m;
        bf16x8 hh, ll;
        #pragma unroll
        for (int j = 0; j < 8; ++j) {
            const float f = src[(size_t)(g * 8 + j) * MM + m_abs];
            const __bf16 hi = (__bf16)f;
            hh[j] = hi;
            ll[j] = (__bf16)(f - (float)hi);
        }
        const size_t o = (size_t)(b * MM + m_abs) * 64 + ((g ^ swz(m)) << 3);
        *reinterpret_cast<bf16x8*>(kt_hi + o) = hh;
        *reinterpret_cast<bf16x8*>(kt_lo + o) = ll;
    }
    for (int tsk = tid; tsk < 512; tsk += 256) {
        const int c = tsk & 63, gm = tsk >> 6;
        const float* p = src + (size_t)c * MM + t * 64 + gm * 8;
        bf16x8 hh;
        #pragma unroll
        for (int j = 0; j < 8; ++j) hh[j] = (__bf16)p[j];
        *reinterpret_cast<bf16x8*>(
            vt + (size_t)(b * CC + c) * MM + t * 64 + ((gm ^ swz(c)) << 3)) = hh;
    }
}

// ---------------- main flash kernel ----------------
template<bool FINAL>
__global__ __launch_bounds__(WAVES * 64, 2)   // no aggressive VGPR cap (R4 lesson)
void attn_main(const __bf16* __restrict__ kt_hi, const __bf16* __restrict__ kt_lo,
               const __bf16* __restrict__ vt, const float* __restrict__ pi,
               float* __restrict__ out, float* __restrict__ opart,
               float* __restrict__ mlpart, const int nsplits)
{
    __shared__ __align__(16) __bf16 k_hi[MTILE][64];        // 8KB
    __shared__ __align__(16) __bf16 k_lo[MTILE][64];        // 8KB
    __shared__ __align__(16) __bf16 v_sm[CC][64];           // 8KB
    __shared__ __align__(16) __bf16 p_sm[WAVES][2][16][64]; // 12KB
    // total 36KB -> 4 blocks/CU resident

    const int tid  = threadIdx.x;
    const int lane = tid & 63;
    const int wave = tid >> 6;     // 0..2
    const int ln   = lane & 15;
    const int lg   = lane >> 4;    // 0..3

    const int b     = blockIdx.z;
    const int split = blockIdx.y;
    const int tpb   = NT / nsplits;
    const int t0s   = split * tpb;
    const int n0    = blockIdx.x * NBLK + wave * NPW;   // this wave's 32 columns

    // ---- Q fragments (hi/lo split), 2 halves, loaded once (verified R3) ----
    bf16x8 qh[2][2], ql[2][2];
    #pragma unroll
    for (int h = 0; h < 2; ++h) {
        const float* qb = pi + (size_t)b * CC * MM + n0 + h * 16 + ln;
        #pragma unroll
        for (int ks = 0; ks < 2; ++ks)
            #pragma unroll
            for (int j = 0; j < 8; ++j) {
                const float f = qb[(size_t)(ks * 32 + lg * 8 + j) * MM];
                const __bf16 hi = (__bf16)f;
                qh[h][ks][j] = hi;
                ql[h][ks][j] = (__bf16)(f - (float)hi);
            }
    }

    f32x4 o[2][4];
    #pragma unroll
    for (int h = 0; h < 2; ++h)
        #pragma unroll
        for (int ct = 0; ct < 4; ++ct) o[h][ct] = (f32x4){0.f, 0.f, 0.f, 0.f};
    float run_max[2] = {-INFINITY, -INFINITY};
    float run_l[2]   = {0.f, 0.f};

    // ---- async staging: 24 x 1KB chunks, 8 per wave, linear LDS dest ----
    auto stage = [&](int t) {
        const size_t kbase = (size_t)(b * MM + t * 64) * 64;   // elements
        #pragma unroll
        for (int q = 0; q < 8; ++q) {
            const int ch = wave * 8 + q;        // wave-uniform, 0..23
            if (ch < 8) {
                gld16(kt_hi + kbase + ch * 512 + lane * 8,
                      (char*)(&k_hi[0][0]) + ch * 1024);
            } else if (ch < 16) {
                const int j = ch - 8;
                gld16(kt_lo + kbase + j * 512 + lane * 8,
                      (char*)(&k_lo[0][0]) + j * 1024);
            } else {
                const int j = ch - 16;
                const int c = j * 8 + (lane >> 3);
                gld16(vt + (size_t)(b * CC + c) * MM + t * 64 + (lane & 7) * 8,
                      (char*)(&v_sm[0][0]) + j * 1024);
            }
        }
    };

    stage(t0s);
    __syncthreads();   // vmcnt drained -> tile 0 ready

    for (int it = 0; it < tpb; ++it) {
        // ---- QK^T: K-frag read once, used by both halves ----
        f32x4 s[2][4];
        #pragma unroll
        for (int h = 0; h < 2; ++h)
            #pragma unroll
            for (int mt = 0; mt < 4; ++mt) s[h][mt] = (f32x4){0.f, 0.f, 0.f, 0.f};
        __builtin_amdgcn_s_setprio(1);
        #pragma unroll
        for (int ks = 0; ks < 2; ++ks) {
            #pragma unroll
            for (int mt = 0; mt < 4; ++mt) {
                const int col = (ks * 32 + lg * 8) ^ (((ln >> 1) ^ mt) << 3);
                const bf16x8 ah = *reinterpret_cast<const bf16x8*>(&k_hi[mt * 16 + ln][col]);
                const bf16x8 al = *reinterpret_cast<const bf16x8*>(&k_lo[mt * 16 + ln][col]);
                #pragma unroll
                for (int h = 0; h < 2; ++h) {
                    s[h][mt] = __builtin_amdgcn_mfma_f32_16x16x32_bf16(ah, qh[h][ks], s[h][mt], 0, 0, 0);
                    s[h][mt] = __builtin_amdgcn_mfma_f32_16x16x32_bf16(ah, ql[h][ks], s[h][mt], 0, 0, 0);
                    s[h][mt] = __builtin_amdgcn_mfma_f32_16x16x32_bf16(al, qh[h][ks], s[h][mt], 0, 0, 0);
                }
            }
        }
        __builtin_amdgcn_s_setprio(0);

        // ---- online softmax per half (T13 defer-rescale, THR=8) ----
        #pragma unroll
        for (int h = 0; h < 2; ++h) {
            float tmax = -INFINITY;
            #pragma unroll
            for (int mt = 0; mt < 4; ++mt)
                #pragma unroll
                for (int r = 0; r < 4; ++r) tmax = fmaxf(tmax, s[h][mt][r]);
            tmax = fmaxf(tmax, __shfl_xor(tmax, 16));
            tmax = fmaxf(tmax, __shfl_xor(tmax, 32));

            float mnew = run_max[h];
            if (!__all(tmax - run_max[h] <= 8.f)) {   // wave-uniform branch
                mnew = fmaxf(run_max[h], tmax);
                const float corr = __expf(run_max[h] - mnew);  // 0 on first iter
                run_l[h] *= corr;
                #pragma unroll
                for (int ct = 0; ct < 4; ++ct) o[h][ct] *= corr;
                run_max[h] = mnew;
            }
            // P = exp(s - mnew), bounded by e^8 when deferred; bf16 handles it.
            float psum = 0.f;
            #pragma unroll
            for (int mt = 0; mt < 4; ++mt) {
                bf16x4 pp;
                #pragma unroll
                for (int r = 0; r < 4; ++r) {
                    const float pv = __expf(s[h][mt][r] - mnew);
                    psum += pv;
                    pp[r] = (__bf16)pv;
                }
                *reinterpret_cast<bf16x4*>(
                    &p_sm[wave][h][ln][(mt * 16 + lg * 4) ^ ((ln >> 1) << 3)]) = pp;
            }
            psum += __shfl_xor(psum, 16);
            psum += __shfl_xor(psum, 32);
            run_l[h] += psum;
        }

        // ---- PV: V-frag read ONCE, feeds both halves ----
        // same-wave LDS write->read on p_sm: in-order, no barrier needed
        __builtin_amdgcn_s_setprio(1);
        #pragma unroll
        for (int ks = 0; ks < 2; ++ks) {
            const int pcol = (ks * 32 + lg * 8) ^ ((ln >> 1) << 3);
            const bf16x8 bp0 = *reinterpret_cast<const bf16x8*>(&p_sm[wave][0][ln][pcol]);
            const bf16x8 bp1 = *reinterpret_cast<const bf16x8*>(&p_sm[wave][1][ln][pcol]);
            #pragma unroll
            for (int ct = 0; ct < 4; ++ct) {
                const int col = (ks * 32 + lg * 8) ^ (((ln >> 1) ^ ct) << 3);
                const bf16x8 av = *reinterpret_cast<const bf16x8*>(&v_sm[ct * 16 + ln][col]);
                o[0][ct] = __builtin_amdgcn_mfma_f32_16x16x32_bf16(av, bp0, o[0][ct], 0, 0, 0);
                o[1][ct] = __builtin_amdgcn_mfma_f32_16x16x32_bf16(av, bp1, o[1][ct], 0, 0, 0);
            }
        }
        __builtin_amdgcn_s_setprio(0);

        __syncthreads();   // all waves done reading k/v -> safe to overwrite
        if (it + 1 < tpb) stage(t0s + it + 1);
        __syncthreads();   // vmcnt drained -> next tile visible
    }

    // ---- epilogue ----
    #pragma unroll
    for (int h = 0; h < 2; ++h) {
        const int n_g = n0 + h * 16 + ln;
        if (FINAL) {
            const float inv = 1.f / run_l[h];
            #pragma unroll
            for (int ct = 0; ct < 4; ++ct)
                #pragma unroll
                for (int r = 0; r < 4; ++r) {
                    const int c = ct * 16 + lg * 4 + r;
                    out[((size_t)b * CC + c) * MM + n_g] = o[h][ct][r] * inv;
                }
        } else {
            const size_t pbase = (size_t)(b * nsplits + split) * CC * MM;
            #pragma unroll
            for (int ct = 0; ct < 4; ++ct)
                #pragma unroll
                for (int r = 0; r < 4; ++r) {
                    const int c = ct * 16 + lg * 4 + r;
                    opart[pbase + (size_t)c * MM + n_g] = o[h][ct][r];
                }
            if (lg == 0) {
                const size_t mb = ((size_t)(b * nsplits + split) * MM + n_g) * 2;
                mlpart[mb]     = run_max[h];
                mlpart[mb + 1] = run_l[h];
            }
        }
    }
}

// out = sum_s O_s * e^{m_s - M} / sum_s l_s * e^{m_s - M}  (4 n per thread)
template<int S>
__global__ __launch_bounds__(256)
void attn_reduce4(const float* __restrict__ opart, const float* __restrict__ mlpart,
                  float* __restrict__ out)
{
    const int t = blockIdx.x * 256 + threadIdx.x;
    if (t >= BB * CC * MM / 4) return;
    const int n  = (t * 4) % MM;
    const int bc = (t * 4) / MM;
    const int b  = bc / CC;
    const int c  = bc - b * CC;

    float wm[S][4], ls[S][4];
    float Mx[4] = {-INFINITY, -INFINITY, -INFINITY, -INFINITY};
    #pragma unroll
    for (int s = 0; s < S; ++s) {
        const float* mp = mlpart + ((size_t)(b * S + s) * MM + n) * 2;
        const float4 a = *reinterpret_cast<const float4*>(mp);
        const float4 q = *reinterpret_cast<const float4*>(mp + 4);
        wm[s][0] = a.x; ls[s][0] = a.y;
        wm[s][1] = a.z; ls[s][1] = a.w;
        wm[s][2] = q.x; ls[s][2] = q.y;
        wm[s][3] = q.z; ls[s][3] = q.w;
        #pragma unroll
        for (int j = 0; j < 4; ++j) Mx[j] = fmaxf(Mx[j], wm[s][j]);
    }
    float L[4] = {0.f, 0.f, 0.f, 0.f};
    #pragma unroll
    for (int s = 0; s < S; ++s)
        #pragma unroll
        for (int j = 0; j < 4; ++j) {
            wm[s][j] = __expf(wm[s][j] - Mx[j]);
            L[j] += ls[s][j] * wm[s][j];
        }
    float acc[4] = {0.f, 0.f, 0.f, 0.f};
    #pragma unroll
    for (int s = 0; s < S; ++s) {
        const float4 o4 = *reinterpret_cast<const float4*>(
            &opart[((size_t)(b * S + s) * CC + c) * MM + n]);
        acc[0] += o4.x * wm[s][0];
        acc[1] += o4.y * wm[s][1];
        acc[2] += o4.z * wm[s][2];
        acc[3] += o4.w * wm[s][3];
    }
    float4 r;
    r.x = acc[0] / L[0]; r.y = acc[1] / L[1];
    r.z = acc[2] / L[2]; r.w = acc[3] / L[3];
    *reinterpret_cast<float4*>(&out[(size_t)t * 4]) = r;
}

extern "C" void kernel_launch(void* const* d_in, const int* in_sizes, int n_in,
                              void* d_out, int out_size, void* d_ws, size_t ws_size,
                              hipStream_t stream) {
    const float* yi = (const float*)d_in[0];   // feature_yi (K = V)
    const float* pi = (const float*)d_in[1];   // feature_pi (Q)
    float* out = (float*)d_out;

    const size_t kelems = (size_t)BB * MM * 64;              // kt_hi / kt_lo elements
    const size_t velems = (size_t)BB * CC * MM;              // vt elements
    const size_t preB   = (kelems * 2 + velems) * 2;         // ~7.1 MB
    auto need = [&](int s) -> size_t {
        return preB + (size_t)BB * s * CC * MM * 4 + (size_t)BB * s * MM * 8;
    };

    int S = 1;
    if (d_ws) {
        if (ws_size >= need(8))      S = 8;   // 1536 blocks, 4 resident/CU
        else if (ws_size >= need(4)) S = 4;
        else if (ws_size >= need(2)) S = 2;
    }
    if (S == 1) return;  // harness ws comfortably exceeds need(2) (R3 ran S=16)

    __bf16* kt_hi = (__bf16*)d_ws;
    __bf16* kt_lo = kt_hi + kelems;
    __bf16* vt    = kt_lo + kelems;
    float* opart  = (float*)(vt + velems);
    float* ml     = opart + (size_t)BB * S * CC * MM;

    prepass<<<dim3(NT, BB), dim3(256), 0, stream>>>(yi, kt_hi, kt_lo, vt);

    attn_main<false><<<dim3(NBX, S, BB), dim3(WAVES * 64), 0, stream>>>(
        kt_hi, kt_lo, vt, pi, out, opart, ml, S);

    const int total4 = BB * CC * MM / 4;
    const dim3 rg((total4 + 255) / 256), rb(256);
    if (S == 8)      attn_reduce4<8><<<rg, rb, 0, stream>>>(opart, ml, out);
    else if (S == 4) attn_reduce4<4><<<rg, rb, 0, stream>>>(opart, ml, out);
    else             attn_reduce4<2><<<rg, rb, 0, stream>>>(opart, ml, out);
}

// Round 6
// 148.136 us; speedup vs baseline: 3.2579x; 1.0713x over previous
//
#include <hip/hip_runtime.h>
#include <hip/hip_bf16.h>

// Problem: B=2, C=64, H=W=96 -> M=N=9216
//   scores[b,m,n] = sum_c yi[b,c,m]*pi[b,c,n] ; weight = softmax over m
//   out[b,c,n]    = sum_m yi[b,c,m]*weight[b,m,n]
// == flash attention with Q=pi (queries n), K=V=yi (keys m), head dim 64.
//
// R6: switch to 32x32x16 MFMA. Score C/D layout (col=lane&31,
// row=(reg&3)+8*(reg>>2)+4*(lane>>5)) puts all rows of column n in lanes
// {n, n+32} -> softmax needs ONE shfl_xor(32), and the PV B-fragment is
// built fully in-register (pack bf16 pairs + one lane^32 exchange per
// k-window) -> p_sm LDS round-trip deleted. LDS 36.9->24 KB -> 6 resident
// 2-wave blocks/CU (6 barrier domains). MFMA issue slots halve (64->32).
// Prepass/staging/swizzle/S=8/T13/T5 carried from R5 (all verified).

#define CC 64
#define MM 9216
#define BB 2
#define WAVES 2
#define NPW 32                 // query columns per wave
#define NBLK (WAVES * NPW)     // 64
#define NBX (MM / NBLK)        // 144
#define MTILE 64
#define NT (MM / MTILE)        // 144

typedef __bf16 bf16x8 __attribute__((ext_vector_type(8)));
typedef float f32x16 __attribute__((ext_vector_type(16)));
typedef unsigned int u32x4 __attribute__((ext_vector_type(4)));

// row-XOR swizzle on 8-element groups (verified R2-R5)
__device__ __forceinline__ int swz(int r) { return ((r >> 1) ^ (r >> 4)) & 7; }

__device__ __forceinline__ void gld16(const void* gsrc, void* ldst) {
    __builtin_amdgcn_global_load_lds(
        (const __attribute__((address_space(1))) void*)gsrc,
        (__attribute__((address_space(3))) void*)ldst, 16, 0, 0);
}

// pack two f32 -> dword of two bf16 (compiler fuses; m240: don't hand-asm)
__device__ __forceinline__ unsigned int pack2(float a, float b) {
    const unsigned short ua = __builtin_bit_cast(unsigned short, (__bf16)a);
    const unsigned short ub = __builtin_bit_cast(unsigned short, (__bf16)b);
    return (unsigned int)ua | ((unsigned int)ub << 16);
}

// ---------------- prepass: bake conversion + transpose + swizzle (verified R3) ----
// kt_hi/kt_lo[b][m][c ^ (swz(m&63)<<3)]  (m-major: one 8KB contiguous block/tile)
// vt[b][c][t*64 + ((m&63) ^ (swz(c)<<3))]
__global__ __launch_bounds__(256)
void prepass(const float* __restrict__ yi, __bf16* __restrict__ kt_hi,
             __bf16* __restrict__ kt_lo, __bf16* __restrict__ vt)
{
    const int t = blockIdx.x;     // key tile 0..143
    const int b = blockIdx.y;
    const int tid = threadIdx.x;  // 256
    const float* src = yi + (size_t)b * CC * MM;

    for (int tsk = tid; tsk < 512; tsk += 256) {
        const int m = tsk & 63, g = tsk >> 6;
        const int m_abs = t * 64 + m;
        bf16x8 hh, ll;
        #pragma unroll
        for (int j = 0; j < 8; ++j) {
            const float f = src[(size_t)(g * 8 + j) * MM + m_abs];
            const __bf16 hi = (__bf16)f;
            hh[j] = hi;
            ll[j] = (__bf16)(f - (float)hi);
        }
        const size_t o = (size_t)(b * MM + m_abs) * 64 + ((g ^ swz(m)) << 3);
        *reinterpret_cast<bf16x8*>(kt_hi + o) = hh;
        *reinterpret_cast<bf16x8*>(kt_lo + o) = ll;
    }
    for (int tsk = tid; tsk < 512; tsk += 256) {
        const int c = tsk & 63, gm = tsk >> 6;
        const float* p = src + (size_t)c * MM + t * 64 + gm * 8;
        bf16x8 hh;
        #pragma unroll
        for (int j = 0; j < 8; ++j) hh[j] = (__bf16)p[j];
        *reinterpret_cast<bf16x8*>(
            vt + (size_t)(b * CC + c) * MM + t * 64 + ((gm ^ swz(c)) << 3)) = hh;
    }
}

// ---------------- main flash kernel (32x32x16 fragments) ----------------
template<bool FINAL>
__global__ __launch_bounds__(WAVES * 64, 2)   // no aggressive VGPR cap (R4 lesson)
void attn_main(const __bf16* __restrict__ kt_hi, const __bf16* __restrict__ kt_lo,
               const __bf16* __restrict__ vt, const float* __restrict__ pi,
               float* __restrict__ out, float* __restrict__ opart,
               float* __restrict__ mlpart, const int nsplits)
{
    __shared__ __align__(16) __bf16 k_hi[MTILE][64];   // 8KB
    __shared__ __align__(16) __bf16 k_lo[MTILE][64];   // 8KB
    __shared__ __align__(16) __bf16 v_sm[CC][64];      // 8KB  -> 24KB total

    const int tid  = threadIdx.x;
    const int lane = tid & 63;
    const int wave = tid >> 6;     // 0..1
    const int l31  = lane & 31;
    const int hi   = lane >> 5;    // 0/1

    const int b     = blockIdx.z;
    const int split = blockIdx.y;
    const int tpb   = NT / nsplits;
    const int t0s   = split * tpb;
    const int n0    = blockIdx.x * NBLK + wave * NPW;
    const int n_g   = n0 + l31;

    // ---- async staging: 24 x 1KB chunks, 12 per wave, linear LDS dest ----
    auto stage = [&](int t) {
        const size_t kbase = (size_t)(b * MM + t * 64) * 64;   // elements
        #pragma unroll
        for (int q = 0; q < 12; ++q) {
            const int ch = wave * 12 + q;        // wave-uniform, 0..23
            if (ch < 8) {
                gld16(kt_hi + kbase + ch * 512 + lane * 8,
                      (char*)(&k_hi[0][0]) + ch * 1024);
            } else if (ch < 16) {
                const int j = ch - 8;
                gld16(kt_lo + kbase + j * 512 + lane * 8,
                      (char*)(&k_lo[0][0]) + j * 1024);
            } else {
                const int j = ch - 16;
                const int c = j * 8 + (lane >> 3);
                gld16(vt + (size_t)(b * CC + c) * MM + t * 64 + (lane & 7) * 8,
                      (char*)(&v_sm[0][0]) + j * 1024);
            }
        }
    };

    stage(t0s);   // DMA in flight while Q loads below

    // ---- Q fragments (hi/lo split): B-operand, col n = l31, k = ks*16+hi*8+j ----
    bf16x8 qh[4], ql[4];
    {
        const float* qb = pi + (size_t)b * CC * MM + n_g;
        #pragma unroll
        for (int ks = 0; ks < 4; ++ks)
            #pragma unroll
            for (int j = 0; j < 8; ++j) {
                const float f = qb[(size_t)(ks * 16 + hi * 8 + j) * MM];
                const __bf16 h = (__bf16)f;
                qh[ks][j] = h;
                ql[ks][j] = (__bf16)(f - (float)h);
            }
    }

    f32x16 o0, o1;
    #pragma unroll
    for (int r = 0; r < 16; ++r) { o0[r] = 0.f; o1[r] = 0.f; }
    float run_max = -INFINITY;
    float run_l   = 0.f;

    const int sx0 = swz(l31) << 3;        // row swizzle, rows 0..31
    const int sx1 = swz(32 + l31) << 3;   // rows 32..63

    __syncthreads();   // vmcnt drained -> tile 0 ready

    for (int it = 0; it < tpb; ++it) {
        // ---- QK^T: S[m 64][n 32], split-bf16 (3 products) ----
        f32x16 s0, s1;
        #pragma unroll
        for (int r = 0; r < 16; ++r) { s0[r] = 0.f; s1[r] = 0.f; }
        __builtin_amdgcn_s_setprio(1);
        #pragma unroll
        for (int ks = 0; ks < 4; ++ks) {
            const int cb = ks * 16 + hi * 8;
            const bf16x8 ah0 = *(const bf16x8*)&k_hi[l31][cb ^ sx0];
            const bf16x8 al0 = *(const bf16x8*)&k_lo[l31][cb ^ sx0];
            const bf16x8 ah1 = *(const bf16x8*)&k_hi[32 + l31][cb ^ sx1];
            const bf16x8 al1 = *(const bf16x8*)&k_lo[32 + l31][cb ^ sx1];
            s0 = __builtin_amdgcn_mfma_f32_32x32x16_bf16(ah0, qh[ks], s0, 0, 0, 0);
            s1 = __builtin_amdgcn_mfma_f32_32x32x16_bf16(ah1, qh[ks], s1, 0, 0, 0);
            s0 = __builtin_amdgcn_mfma_f32_32x32x16_bf16(ah0, ql[ks], s0, 0, 0, 0);
            s1 = __builtin_amdgcn_mfma_f32_32x32x16_bf16(ah1, ql[ks], s1, 0, 0, 0);
            s0 = __builtin_amdgcn_mfma_f32_32x32x16_bf16(al0, qh[ks], s0, 0, 0, 0);
            s1 = __builtin_amdgcn_mfma_f32_32x32x16_bf16(al1, qh[ks], s1, 0, 0, 0);
        }
        __builtin_amdgcn_s_setprio(0);

        // ---- online softmax over m; rows of col n live in lanes {n, n+32} ----
        float t8[8];
        #pragma unroll
        for (int r = 0; r < 8; ++r)
            t8[r] = fmaxf(fmaxf(s0[r], s0[r + 8]), fmaxf(s1[r], s1[r + 8]));
        float tmax = fmaxf(fmaxf(fmaxf(t8[0], t8[1]), fmaxf(t8[2], t8[3])),
                           fmaxf(fmaxf(t8[4], t8[5]), fmaxf(t8[6], t8[7])));
        tmax = fmaxf(tmax, __shfl_xor(tmax, 32));

        if (!__all(tmax - run_max <= 8.f)) {   // T13 defer-rescale (wave-uniform)
            const float mnew = fmaxf(run_max, tmax);
            const float corr = __expf(run_max - mnew);  // 0 on first iter
            run_l *= corr;
            #pragma unroll
            for (int r = 0; r < 16; ++r) { o0[r] *= corr; o1[r] *= corr; }
            run_max = mnew;
        }

        float ps[8];
        #pragma unroll
        for (int r = 0; r < 8; ++r) {
            s0[r]     = __expf(s0[r]     - run_max);
            s0[r + 8] = __expf(s0[r + 8] - run_max);
            s1[r]     = __expf(s1[r]     - run_max);
            s1[r + 8] = __expf(s1[r + 8] - run_max);
            ps[r] = (s0[r] + s0[r + 8]) + (s1[r] + s1[r + 8]);
        }
        float psum = ((ps[0] + ps[1]) + (ps[2] + ps[3])) +
                     ((ps[4] + ps[5]) + (ps[6] + ps[7]));
        psum += __shfl_xor(psum, 32);
        run_l += psum;

        // ---- pack P to bf16 dwords: X[mt][q][d] = pack(p[4q+2d], p[4q+2d+1]) ----
        unsigned int X[2][4][2];
        #pragma unroll
        for (int q = 0; q < 4; ++q)
            #pragma unroll
            for (int d = 0; d < 2; ++d) {
                X[0][q][d] = pack2(s0[4 * q + 2 * d], s0[4 * q + 2 * d + 1]);
                X[1][q][d] = pack2(s1[4 * q + 2 * d], s1[4 * q + 2 * d + 1]);
            }

        // ---- PV: B-frag built in-register (one lane^32 exchange per k-window) ----
        __builtin_amdgcn_s_setprio(1);
        #pragma unroll
        for (int ks = 0; ks < 4; ++ks) {
            const int mt = ks >> 1, e = ks & 1;
            const unsigned int A0 = X[mt][2 * e][0],     A1 = X[mt][2 * e][1];
            const unsigned int B0 = X[mt][2 * e + 1][0], B1 = X[mt][2 * e + 1][1];
            // partner (hi=0 lane) needs my A-pair; partner (hi=1) needs my B-pair
            const unsigned int r0 = __shfl_xor(hi ? A0 : B0, 32);
            const unsigned int r1 = __shfl_xor(hi ? A1 : B1, 32);
            u32x4 w;
            w.x = hi ? r0 : A0;   // j=0..1
            w.y = hi ? r1 : A1;   // j=2..3
            w.z = hi ? B0 : r0;   // j=4..5
            w.w = hi ? B1 : r1;   // j=6..7
            const bf16x8 bp = __builtin_bit_cast(bf16x8, w);

            const int cb = ks * 16 + hi * 8;
            const bf16x8 av0 = *(const bf16x8*)&v_sm[l31][cb ^ sx0];
            const bf16x8 av1 = *(const bf16x8*)&v_sm[32 + l31][cb ^ sx1];
            o0 = __builtin_amdgcn_mfma_f32_32x32x16_bf16(av0, bp, o0, 0, 0, 0);
            o1 = __builtin_amdgcn_mfma_f32_32x32x16_bf16(av1, bp, o1, 0, 0, 0);
        }
        __builtin_amdgcn_s_setprio(0);

        __syncthreads();   // all waves done reading k/v -> safe to overwrite
        if (it + 1 < tpb) stage(t0s + it + 1);
        __syncthreads();   // vmcnt drained -> next tile visible
    }

    // ---- epilogue: c = ct*32 + (r&3) + 8*(r>>2) + 4*hi ----
    if (FINAL) {
        const float inv = 1.f / run_l;
        #pragma unroll
        for (int r = 0; r < 16; ++r) {
            const int cl = (r & 3) + 8 * (r >> 2) + 4 * hi;
            out[((size_t)b * CC + cl) * MM + n_g]      = o0[r] * inv;
            out[((size_t)b * CC + cl + 32) * MM + n_g] = o1[r] * inv;
        }
    } else {
        const size_t pbase = (size_t)(b * nsplits + split) * CC * MM;
        #pragma unroll
        for (int r = 0; r < 16; ++r) {
            const int cl = (r & 3) + 8 * (r >> 2) + 4 * hi;
            opart[pbase + (size_t)cl * MM + n_g]        = o0[r];
            opart[pbase + (size_t)(cl + 32) * MM + n_g] = o1[r];
        }
        if (hi == 0) {   // lanes n and n+32 hold identical (run_max, run_l)
            const size_t mb = ((size_t)(b * nsplits + split) * MM + n_g) * 2;
            mlpart[mb]     = run_max;
            mlpart[mb + 1] = run_l;
        }
    }
}

// out = sum_s O_s * e^{m_s - M} / sum_s l_s * e^{m_s - M}  (4 n per thread)
template<int S>
__global__ __launch_bounds__(256)
void attn_reduce4(const float* __restrict__ opart, const float* __restrict__ mlpart,
                  float* __restrict__ out)
{
    const int t = blockIdx.x * 256 + threadIdx.x;
    if (t >= BB * CC * MM / 4) return;
    const int n  = (t * 4) % MM;
    const int bc = (t * 4) / MM;
    const int b  = bc / CC;
    const int c  = bc - b * CC;

    float wm[S][4], ls[S][4];
    float Mx[4] = {-INFINITY, -INFINITY, -INFINITY, -INFINITY};
    #pragma unroll
    for (int s = 0; s < S; ++s) {
        const float* mp = mlpart + ((size_t)(b * S + s) * MM + n) * 2;
        const float4 a = *reinterpret_cast<const float4*>(mp);
        const float4 q = *reinterpret_cast<const float4*>(mp + 4);
        wm[s][0] = a.x; ls[s][0] = a.y;
        wm[s][1] = a.z; ls[s][1] = a.w;
        wm[s][2] = q.x; ls[s][2] = q.y;
        wm[s][3] = q.z; ls[s][3] = q.w;
        #pragma unroll
        for (int j = 0; j < 4; ++j) Mx[j] = fmaxf(Mx[j], wm[s][j]);
    }
    float L[4] = {0.f, 0.f, 0.f, 0.f};
    #pragma unroll
    for (int s = 0; s < S; ++s)
        #pragma unroll
        for (int j = 0; j < 4; ++j) {
            wm[s][j] = __expf(wm[s][j] - Mx[j]);
            L[j] += ls[s][j] * wm[s][j];
        }
    float acc[4] = {0.f, 0.f, 0.f, 0.f};
    #pragma unroll
    for (int s = 0; s < S; ++s) {
        const float4 o4 = *reinterpret_cast<const float4*>(
            &opart[((size_t)(b * S + s) * CC + c) * MM + n]);
        acc[0] += o4.x * wm[s][0];
        acc[1] += o4.y * wm[s][1];
        acc[2] += o4.z * wm[s][2];
        acc[3] += o4.w * wm[s][3];
    }
    float4 r;
    r.x = acc[0] / L[0]; r.y = acc[1] / L[1];
    r.z = acc[2] / L[2]; r.w = acc[3] / L[3];
    *reinterpret_cast<float4*>(&out[(size_t)t * 4]) = r;
}

extern "C" void kernel_launch(void* const* d_in, const int* in_sizes, int n_in,
                              void* d_out, int out_size, void* d_ws, size_t ws_size,
                              hipStream_t stream) {
    const float* yi = (const float*)d_in[0];   // feature_yi (K = V)
    const float* pi = (const float*)d_in[1];   // feature_pi (Q)
    float* out = (float*)d_out;

    const size_t kelems = (size_t)BB * MM * 64;              // kt_hi / kt_lo elements
    const size_t velems = (size_t)BB * CC * MM;              // vt elements
    const size_t preB   = (kelems * 2 + velems) * 2;         // ~7.1 MB
    auto need = [&](int s) -> size_t {
        return preB + (size_t)BB * s * CC * MM * 4 + (size_t)BB * s * MM * 8;
    };

    int S = 1;
    if (d_ws) {
        if (ws_size >= need(8))      S = 8;   // 2304 blocks, 6 resident/CU
        else if (ws_size >= need(4)) S = 4;
        else if (ws_size >= need(2)) S = 2;
    }

    if (S == 1) {
        // needs only the prepacked inputs (~7.1 MB); no partials
        if (!d_ws || ws_size < preB) return;
        __bf16* kt_hi = (__bf16*)d_ws;
        __bf16* kt_lo = kt_hi + kelems;
        __bf16* vt    = kt_lo + kelems;
        prepass<<<dim3(NT, BB), dim3(256), 0, stream>>>(yi, kt_hi, kt_lo, vt);
        attn_main<true><<<dim3(NBX, 1, BB), dim3(WAVES * 64), 0, stream>>>(
            kt_hi, kt_lo, vt, pi, out, out, out, 1);
        return;
    }

    __bf16* kt_hi = (__bf16*)d_ws;
    __bf16* kt_lo = kt_hi + kelems;
    __bf16* vt    = kt_lo + kelems;
    float* opart  = (float*)(vt + velems);
    float* ml     = opart + (size_t)BB * S * CC * MM;

    prepass<<<dim3(NT, BB), dim3(256), 0, stream>>>(yi, kt_hi, kt_lo, vt);

    attn_main<false><<<dim3(NBX, S, BB), dim3(WAVES * 64), 0, stream>>>(
        kt_hi, kt_lo, vt, pi, out, opart, ml, S);

    const int total4 = BB * CC * MM / 4;
    const dim3 rg((total4 + 255) / 256), rb(256);
    if (S == 8)      attn_reduce4<8><<<rg, rb, 0, stream>>>(opart, ml, out);
    else if (S == 4) attn_reduce4<4><<<rg, rb, 0, stream>>>(opart, ml, out);
    else             attn_reduce4<2><<<rg, rb, 0, stream>>>(opart, ml, out);
}

// Round 8
// 147.166 us; speedup vs baseline: 3.2794x; 1.0066x over previous
//
#include <hip/hip_runtime.h>
#include <hip/hip_bf16.h>

// Problem: B=2, C=64, H=W=96 -> M=N=9216
//   scores[b,m,n] = sum_c yi[b,c,m]*pi[b,c,n] ; weight = softmax over m
//   out[b,c,n]    = sum_m yi[b,c,m]*weight[b,m,n]
// == flash attention with Q=pi (queries n), K=V=yi (keys m), head dim 64.
//
// R8: R7 failed at absmax 2^30 -- root cause: permlane32_swap(v, v) with the
// SAME value as both operands; the instruction swaps register halves in
// place, so with aliased operands both results collapse to the partner half
// and each lane loses its own half of the max/sum reduction -> understated
// run_max -> P = 2^(s-run_max) blows up. Fix: revert ALL cross-lane
// exchanges to the R6-verified __shfl_xor forms. Keep R7's two safe changes:
//  (1) XCD-locality remap for S=8 (bijective, re-enumerated): all 144
//      n-blocks of a (b,split) group on one XCD -> 432KB K/V set L2-resident
//      (was 995MB/launch of tile re-staging served by L3).
//  (2) log2-domain softmax (exact reparametrization; native v_exp_f32,
//      threshold 11.09 in log2 == e^8).

#define CC 64
#define MM 9216
#define BB 2
#define WAVES 2
#define NPW 32                 // query columns per wave
#define NBLK (WAVES * NPW)     // 64
#define NBX (MM / NBLK)        // 144
#define MTILE 64
#define NT (MM / MTILE)        // 144

typedef __bf16 bf16x8 __attribute__((ext_vector_type(8)));
typedef float f32x16 __attribute__((ext_vector_type(16)));
typedef unsigned int u32x4 __attribute__((ext_vector_type(4)));

// row-XOR swizzle on 8-element groups (verified R2-R6)
__device__ __forceinline__ int swz(int r) { return ((r >> 1) ^ (r >> 4)) & 7; }

__device__ __forceinline__ void gld16(const void* gsrc, void* ldst) {
    __builtin_amdgcn_global_load_lds(
        (const __attribute__((address_space(1))) void*)gsrc,
        (__attribute__((address_space(3))) void*)ldst, 16, 0, 0);
}

// native 2^x
__device__ __forceinline__ float fexp2(float x) {
#if __has_builtin(__builtin_amdgcn_exp2f)
    return __builtin_amdgcn_exp2f(x);
#else
    return exp2f(x);
#endif
}

// pack two f32 -> dword of two bf16
__device__ __forceinline__ unsigned int pack2(float a, float b) {
    const unsigned short ua = __builtin_bit_cast(unsigned short, (__bf16)a);
    const unsigned short ub = __builtin_bit_cast(unsigned short, (__bf16)b);
    return (unsigned int)ua | ((unsigned int)ub << 16);
}

// ---------------- prepass: bake conversion + transpose + swizzle (verified R3) ----
// kt_hi/kt_lo[b][m][c ^ (swz(m&63)<<3)]  (m-major: one 8KB contiguous block/tile)
// vt[b][c][t*64 + ((m&63) ^ (swz(c)<<3))]
__global__ __launch_bounds__(256)
void prepass(const float* __restrict__ yi, __bf16* __restrict__ kt_hi,
             __bf16* __restrict__ kt_lo, __bf16* __restrict__ vt)
{
    const int t = blockIdx.x;     // key tile 0..143
    const int b = blockIdx.y;
    const int tid = threadIdx.x;  // 256
    const float* src = yi + (size_t)b * CC * MM;

    for (int tsk = tid; tsk < 512; tsk += 256) {
        const int m = tsk & 63, g = tsk >> 6;
        const int m_abs = t * 64 + m;
        bf16x8 hh, ll;
        #pragma unroll
        for (int j = 0; j < 8; ++j) {
            const float f = src[(size_t)(g * 8 + j) * MM + m_abs];
            const __bf16 hi = (__bf16)f;
            hh[j] = hi;
            ll[j] = (__bf16)(f - (float)hi);
        }
        const size_t o = (size_t)(b * MM + m_abs) * 64 + ((g ^ swz(m)) << 3);
        *reinterpret_cast<bf16x8*>(kt_hi + o) = hh;
        *reinterpret_cast<bf16x8*>(kt_lo + o) = ll;
    }
    for (int tsk = tid; tsk < 512; tsk += 256) {
        const int c = tsk & 63, gm = tsk >> 6;
        const float* p = src + (size_t)c * MM + t * 64 + gm * 8;
        bf16x8 hh;
        #pragma unroll
        for (int j = 0; j < 8; ++j) hh[j] = (__bf16)p[j];
        *reinterpret_cast<bf16x8*>(
            vt + (size_t)(b * CC + c) * MM + t * 64 + ((gm ^ swz(c)) << 3)) = hh;
    }
}

// ---------------- main flash kernel (32x32x16 fragments, log2-domain softmax) ----
template<bool FINAL>
__global__ __launch_bounds__(WAVES * 64, 2)
void attn_main(const __bf16* __restrict__ kt_hi, const __bf16* __restrict__ kt_lo,
               const __bf16* __restrict__ vt, const float* __restrict__ pi,
               float* __restrict__ out, float* __restrict__ opart,
               float* __restrict__ mlpart, const int nsplits)
{
    __shared__ __align__(16) __bf16 k_hi[MTILE][64];   // 8KB
    __shared__ __align__(16) __bf16 k_lo[MTILE][64];   // 8KB
    __shared__ __align__(16) __bf16 v_sm[CC][64];      // 8KB  -> 24KB total

    const int tid  = threadIdx.x;
    const int lane = tid & 63;
    const int wave = tid >> 6;     // 0..1
    const int l31  = lane & 31;
    const int hi   = lane >> 5;    // 0/1

    // ---- block decode: XCD-locality map when S==8 (1D grid), else plain 3D ----
    int bx, split, b;
    if (nsplits == 8 && gridDim.y == 1) {
        const int bid = blockIdx.x;           // 0..2303
        const int xcd = bid & 7, slot = bid >> 3;
        bx = slot % NBX;                      // n-block 0..143
        const int g = xcd + 8 * (slot / NBX); // group 0..15, all blocks on one XCD
        split = g & 7;
        b     = g >> 3;
    } else {
        bx = blockIdx.x; split = blockIdx.y; b = blockIdx.z;
    }

    const int tpb = NT / nsplits;
    const int t0s = split * tpb;
    const int n0  = bx * NBLK + wave * NPW;
    const int n_g = n0 + l31;

    // ---- async staging: 24 x 1KB chunks, 12 per wave, linear LDS dest ----
    auto stage = [&](int t) {
        const size_t kbase = (size_t)(b * MM + t * 64) * 64;   // elements
        #pragma unroll
        for (int q = 0; q < 12; ++q) {
            const int ch = wave * 12 + q;        // wave-uniform, 0..23
            if (ch < 8) {
                gld16(kt_hi + kbase + ch * 512 + lane * 8,
                      (char*)(&k_hi[0][0]) + ch * 1024);
            } else if (ch < 16) {
                const int j = ch - 8;
                gld16(kt_lo + kbase + j * 512 + lane * 8,
                      (char*)(&k_lo[0][0]) + j * 1024);
            } else {
                const int j = ch - 16;
                const int c = j * 8 + (lane >> 3);
                gld16(vt + (size_t)(b * CC + c) * MM + t * 64 + (lane & 7) * 8,
                      (char*)(&v_sm[0][0]) + j * 1024);
            }
        }
    };

    stage(t0s);   // DMA in flight while Q loads below

    // ---- Q fragments (hi/lo split), log2e folded in: s = log2e * (q.k) ----
    const float LOG2E = 1.4426950408889634f;
    bf16x8 qh[4], ql[4];
    {
        const float* qb = pi + (size_t)b * CC * MM + n_g;
        #pragma unroll
        for (int ks = 0; ks < 4; ++ks)
            #pragma unroll
            for (int j = 0; j < 8; ++j) {
                const float f = qb[(size_t)(ks * 16 + hi * 8 + j) * MM] * LOG2E;
                const __bf16 h = (__bf16)f;
                qh[ks][j] = h;
                ql[ks][j] = (__bf16)(f - (float)h);
            }
    }

    f32x16 o0, o1;
    #pragma unroll
    for (int r = 0; r < 16; ++r) { o0[r] = 0.f; o1[r] = 0.f; }
    float run_max = -INFINITY;   // log2-domain
    float run_l   = 0.f;

    const int sx0 = swz(l31) << 3;        // row swizzle, rows 0..31
    const int sx1 = swz(32 + l31) << 3;   // rows 32..63

    __syncthreads();   // vmcnt drained -> tile 0 ready

    for (int it = 0; it < tpb; ++it) {
        // ---- QK^T: S[m 64][n 32], split-bf16 (3 products) ----
        f32x16 s0, s1;
        #pragma unroll
        for (int r = 0; r < 16; ++r) { s0[r] = 0.f; s1[r] = 0.f; }
        __builtin_amdgcn_s_setprio(1);
        #pragma unroll
        for (int ks = 0; ks < 4; ++ks) {
            const int cb = ks * 16 + hi * 8;
            const bf16x8 ah0 = *(const bf16x8*)&k_hi[l31][cb ^ sx0];
            const bf16x8 al0 = *(const bf16x8*)&k_lo[l31][cb ^ sx0];
            const bf16x8 ah1 = *(const bf16x8*)&k_hi[32 + l31][cb ^ sx1];
            const bf16x8 al1 = *(const bf16x8*)&k_lo[32 + l31][cb ^ sx1];
            s0 = __builtin_amdgcn_mfma_f32_32x32x16_bf16(ah0, qh[ks], s0, 0, 0, 0);
            s1 = __builtin_amdgcn_mfma_f32_32x32x16_bf16(ah1, qh[ks], s1, 0, 0, 0);
            s0 = __builtin_amdgcn_mfma_f32_32x32x16_bf16(ah0, ql[ks], s0, 0, 0, 0);
            s1 = __builtin_amdgcn_mfma_f32_32x32x16_bf16(ah1, ql[ks], s1, 0, 0, 0);
            s0 = __builtin_amdgcn_mfma_f32_32x32x16_bf16(al0, qh[ks], s0, 0, 0, 0);
            s1 = __builtin_amdgcn_mfma_f32_32x32x16_bf16(al1, qh[ks], s1, 0, 0, 0);
        }
        __builtin_amdgcn_s_setprio(0);

        // ---- online softmax (log2-domain); rows of col n live in lanes {n, n+32} ----
        float t8[8];
        #pragma unroll
        for (int r = 0; r < 8; ++r)
            t8[r] = fmaxf(fmaxf(s0[r], s0[r + 8]), fmaxf(s1[r], s1[r + 8]));
        float tmax = fmaxf(fmaxf(fmaxf(t8[0], t8[1]), fmaxf(t8[2], t8[3])),
                           fmaxf(fmaxf(t8[4], t8[5]), fmaxf(t8[6], t8[7])));
        tmax = fmaxf(tmax, __shfl_xor(tmax, 32));   // R6-verified reduce

        if (!__all(tmax - run_max <= 11.09f)) {   // T13 defer (11.09 log2 == e^8)
            const float mnew = fmaxf(run_max, tmax);
            const float corr = fexp2(run_max - mnew);  // 0 on first iter
            run_l *= corr;
            #pragma unroll
            for (int r = 0; r < 16; ++r) { o0[r] *= corr; o1[r] *= corr; }
            run_max = mnew;
        }

        float ps[8];
        #pragma unroll
        for (int r = 0; r < 8; ++r) {
            s0[r]     = fexp2(s0[r]     - run_max);
            s0[r + 8] = fexp2(s0[r + 8] - run_max);
            s1[r]     = fexp2(s1[r]     - run_max);
            s1[r + 8] = fexp2(s1[r + 8] - run_max);
            ps[r] = (s0[r] + s0[r + 8]) + (s1[r] + s1[r + 8]);
        }
        float psum = ((ps[0] + ps[1]) + (ps[2] + ps[3])) +
                     ((ps[4] + ps[5]) + (ps[6] + ps[7]));
        psum += __shfl_xor(psum, 32);               // R6-verified reduce
        run_l += psum;

        // ---- pack P to bf16 dwords: X[mt][q][d] = pack(p[4q+2d], p[4q+2d+1]) ----
        unsigned int X[2][4][2];
        #pragma unroll
        for (int q = 0; q < 4; ++q)
            #pragma unroll
            for (int d = 0; d < 2; ++d) {
                X[0][q][d] = pack2(s0[4 * q + 2 * d], s0[4 * q + 2 * d + 1]);
                X[1][q][d] = pack2(s1[4 * q + 2 * d], s1[4 * q + 2 * d + 1]);
            }

        // ---- PV: B-frag via shfl_xor + selects (R6-verified exchange) ----
        __builtin_amdgcn_s_setprio(1);
        #pragma unroll
        for (int ks = 0; ks < 4; ++ks) {
            const int mt = ks >> 1, e = ks & 1;
            const unsigned int A0 = X[mt][2 * e][0],     A1 = X[mt][2 * e][1];
            const unsigned int B0 = X[mt][2 * e + 1][0], B1 = X[mt][2 * e + 1][1];
            // partner (hi=0 lane) needs my A-pair; partner (hi=1) needs my B-pair
            const unsigned int r0 = __shfl_xor(hi ? A0 : B0, 32);
            const unsigned int r1 = __shfl_xor(hi ? A1 : B1, 32);
            u32x4 w;
            w.x = hi ? r0 : A0;   // j=0..1
            w.y = hi ? r1 : A1;   // j=2..3
            w.z = hi ? B0 : r0;   // j=4..5
            w.w = hi ? B1 : r1;   // j=6..7
            const bf16x8 bp = __builtin_bit_cast(bf16x8, w);

            const int cb = ks * 16 + hi * 8;
            const bf16x8 av0 = *(const bf16x8*)&v_sm[l31][cb ^ sx0];
            const bf16x8 av1 = *(const bf16x8*)&v_sm[32 + l31][cb ^ sx1];
            o0 = __builtin_amdgcn_mfma_f32_32x32x16_bf16(av0, bp, o0, 0, 0, 0);
            o1 = __builtin_amdgcn_mfma_f32_32x32x16_bf16(av1, bp, o1, 0, 0, 0);
        }
        __builtin_amdgcn_s_setprio(0);

        __syncthreads();   // all waves done reading k/v -> safe to overwrite
        if (it + 1 < tpb) stage(t0s + it + 1);
        __syncthreads();   // vmcnt drained -> next tile visible
    }

    // ---- epilogue: c = (r&3) + 8*(r>>2) + 4*hi ----
    if (FINAL) {
        const float inv = 1.f / run_l;
        #pragma unroll
        for (int r = 0; r < 16; ++r) {
            const int cl = (r & 3) + 8 * (r >> 2) + 4 * hi;
            out[((size_t)b * CC + cl) * MM + n_g]      = o0[r] * inv;
            out[((size_t)b * CC + cl + 32) * MM + n_g] = o1[r] * inv;
        }
    } else {
        const size_t pbase = (size_t)(b * nsplits + split) * CC * MM;
        #pragma unroll
        for (int r = 0; r < 16; ++r) {
            const int cl = (r & 3) + 8 * (r >> 2) + 4 * hi;
            opart[pbase + (size_t)cl * MM + n_g]        = o0[r];
            opart[pbase + (size_t)(cl + 32) * MM + n_g] = o1[r];
        }
        if (hi == 0) {   // lanes n and n+32 hold identical (run_max, run_l)
            const size_t mb = ((size_t)(b * nsplits + split) * MM + n_g) * 2;
            mlpart[mb]     = run_max;   // log2-domain
            mlpart[mb + 1] = run_l;
        }
    }
}

// out = sum_s O_s * 2^{m_s - M} / sum_s l_s * 2^{m_s - M}  (4 n per thread)
template<int S>
__global__ __launch_bounds__(256)
void attn_reduce4(const float* __restrict__ opart, const float* __restrict__ mlpart,
                  float* __restrict__ out)
{
    const int t = blockIdx.x * 256 + threadIdx.x;
    if (t >= BB * CC * MM / 4) return;
    const int n  = (t * 4) % MM;
    const int bc = (t * 4) / MM;
    const int b  = bc / CC;
    const int c  = bc - b * CC;

    float wm[S][4], ls[S][4];
    float Mx[4] = {-INFINITY, -INFINITY, -INFINITY, -INFINITY};
    #pragma unroll
    for (int s = 0; s < S; ++s) {
        const float* mp = mlpart + ((size_t)(b * S + s) * MM + n) * 2;
        const float4 a = *reinterpret_cast<const float4*>(mp);
        const float4 q = *reinterpret_cast<const float4*>(mp + 4);
        wm[s][0] = a.x; ls[s][0] = a.y;
        wm[s][1] = a.z; ls[s][1] = a.w;
        wm[s][2] = q.x; ls[s][2] = q.y;
        wm[s][3] = q.z; ls[s][3] = q.w;
        #pragma unroll
        for (int j = 0; j < 4; ++j) Mx[j] = fmaxf(Mx[j], wm[s][j]);
    }
    float L[4] = {0.f, 0.f, 0.f, 0.f};
    #pragma unroll
    for (int s = 0; s < S; ++s)
        #pragma unroll
        for (int j = 0; j < 4; ++j) {
            wm[s][j] = fexp2(wm[s][j] - Mx[j]);   // log2-domain weights
            L[j] += ls[s][j] * wm[s][j];
        }
    float acc[4] = {0.f, 0.f, 0.f, 0.f};
    #pragma unroll
    for (int s = 0; s < S; ++s) {
        const float4 o4 = *reinterpret_cast<const float4*>(
            &opart[((size_t)(b * S + s) * CC + c) * MM + n]);
        acc[0] += o4.x * wm[s][0];
        acc[1] += o4.y * wm[s][1];
        acc[2] += o4.z * wm[s][2];
        acc[3] += o4.w * wm[s][3];
    }
    float4 r;
    r.x = acc[0] / L[0]; r.y = acc[1] / L[1];
    r.z = acc[2] / L[2]; r.w = acc[3] / L[3];
    *reinterpret_cast<float4*>(&out[(size_t)t * 4]) = r;
}

extern "C" void kernel_launch(void* const* d_in, const int* in_sizes, int n_in,
                              void* d_out, int out_size, void* d_ws, size_t ws_size,
                              hipStream_t stream) {
    const float* yi = (const float*)d_in[0];   // feature_yi (K = V)
    const float* pi = (const float*)d_in[1];   // feature_pi (Q)
    float* out = (float*)d_out;

    const size_t kelems = (size_t)BB * MM * 64;              // kt_hi / kt_lo elements
    const size_t velems = (size_t)BB * CC * MM;              // vt elements
    const size_t preB   = (kelems * 2 + velems) * 2;         // ~7.1 MB
    auto need = [&](int s) -> size_t {
        return preB + (size_t)BB * s * CC * MM * 4 + (size_t)BB * s * MM * 8;
    };

    int S = 1;
    if (d_ws) {
        if (ws_size >= need(8))      S = 8;
        else if (ws_size >= need(4)) S = 4;
        else if (ws_size >= need(2)) S = 2;
    }

    if (S == 1) {
        if (!d_ws || ws_size < preB) return;
        __bf16* kt_hi = (__bf16*)d_ws;
        __bf16* kt_lo = kt_hi + kelems;
        __bf16* vt    = kt_lo + kelems;
        prepass<<<dim3(NT, BB), dim3(256), 0, stream>>>(yi, kt_hi, kt_lo, vt);
        attn_main<true><<<dim3(NBX, 1, BB), dim3(WAVES * 64), 0, stream>>>(
            kt_hi, kt_lo, vt, pi, out, out, out, 1);
        return;
    }

    __bf16* kt_hi = (__bf16*)d_ws;
    __bf16* kt_lo = kt_hi + kelems;
    __bf16* vt    = kt_lo + kelems;
    float* opart  = (float*)(vt + velems);
    float* ml     = opart + (size_t)BB * S * CC * MM;

    prepass<<<dim3(NT, BB), dim3(256), 0, stream>>>(yi, kt_hi, kt_lo, vt);

    if (S == 8) {
        // 1D grid, XCD-locality mapping (all 144 n-blocks of a (b,split)
        // group land on one XCD; its ~864KB K/V working set fits 4MB L2)
        attn_main<false><<<dim3(NBX * 8 * BB), dim3(WAVES * 64), 0, stream>>>(
            kt_hi, kt_lo, vt, pi, out, opart, ml, 8);
    } else {
        attn_main<false><<<dim3(NBX, S, BB), dim3(WAVES * 64), 0, stream>>>(
            kt_hi, kt_lo, vt, pi, out, opart, ml, S);
    }

    const int total4 = BB * CC * MM / 4;
    const dim3 rg((total4 + 255) / 256), rb(256);
    if (S == 8)      attn_reduce4<8><<<rg, rb, 0, stream>>>(opart, ml, out);
    else if (S == 4) attn_reduce4<4><<<rg, rb, 0, stream>>>(opart, ml, out);
    else             attn_reduce4<2><<<rg, rb, 0, stream>>>(opart, ml, out);
}

// Round 9
// 136.677 us; speedup vs baseline: 3.5310x; 1.0767x over previous
//
#include <hip/hip_runtime.h>
#include <hip/hip_bf16.h>

// Problem: B=2, C=64, H=W=96 -> M=N=9216
//   scores[b,m,n] = sum_c yi[b,c,m]*pi[b,c,n] ; weight = softmax over m
//   out[b,c,n]    = sum_m yi[b,c,m]*weight[b,m,n]
// == flash attention with Q=pi (queries n), K=V=yi (keys m), head dim 64.
//
// R9: R8 showed wall ~= sum of pipe busy times at 1.4 waves/SIMD -- TLP-bound,
// not staging-bound (XCD remap moved FETCH 32->23MB, dur unchanged). Fix is
// pure packing: WAVES 2->4 per block (NBLK=128, NBX=72) at the SAME 24KB LDS
// and same per-wave code -> 4 blocks/CU x 4 waves = 16 waves/CU (4/SIMD),
// ~3x effective TLP; K-tile re-staging halves (72 blocks/group vs 144).
// Everything else carried from R8 (verified): 32x32x16 MFMA, in-register PV
// exchange via shfl_xor, log2-domain softmax + T13 defer, prepacked
// swizzled global staging via global_load_lds, S=8 split-K + reduce.

#define CC 64
#define MM 9216
#define BB 2
#define WAVES 4
#define NPW 32                 // query columns per wave
#define NBLK (WAVES * NPW)     // 128
#define NBX (MM / NBLK)        // 72
#define MTILE 64
#define NT (MM / MTILE)        // 144

typedef __bf16 bf16x8 __attribute__((ext_vector_type(8)));
typedef float f32x16 __attribute__((ext_vector_type(16)));
typedef unsigned int u32x4 __attribute__((ext_vector_type(4)));

// row-XOR swizzle on 8-element groups (verified R2-R8)
__device__ __forceinline__ int swz(int r) { return ((r >> 1) ^ (r >> 4)) & 7; }

__device__ __forceinline__ void gld16(const void* gsrc, void* ldst) {
    __builtin_amdgcn_global_load_lds(
        (const __attribute__((address_space(1))) void*)gsrc,
        (__attribute__((address_space(3))) void*)ldst, 16, 0, 0);
}

// native 2^x
__device__ __forceinline__ float fexp2(float x) {
#if __has_builtin(__builtin_amdgcn_exp2f)
    return __builtin_amdgcn_exp2f(x);
#else
    return exp2f(x);
#endif
}

// pack two f32 -> dword of two bf16
__device__ __forceinline__ unsigned int pack2(float a, float b) {
    const unsigned short ua = __builtin_bit_cast(unsigned short, (__bf16)a);
    const unsigned short ub = __builtin_bit_cast(unsigned short, (__bf16)b);
    return (unsigned int)ua | ((unsigned int)ub << 16);
}

// ---------------- prepass: bake conversion + transpose + swizzle (verified R3) ----
// kt_hi/kt_lo[b][m][c ^ (swz(m&63)<<3)]  (m-major: one 8KB contiguous block/tile)
// vt[b][c][t*64 + ((m&63) ^ (swz(c)<<3))]
__global__ __launch_bounds__(256)
void prepass(const float* __restrict__ yi, __bf16* __restrict__ kt_hi,
             __bf16* __restrict__ kt_lo, __bf16* __restrict__ vt)
{
    const int t = blockIdx.x;     // key tile 0..143
    const int b = blockIdx.y;
    const int tid = threadIdx.x;  // 256
    const float* src = yi + (size_t)b * CC * MM;

    for (int tsk = tid; tsk < 512; tsk += 256) {
        const int m = tsk & 63, g = tsk >> 6;
        const int m_abs = t * 64 + m;
        bf16x8 hh, ll;
        #pragma unroll
        for (int j = 0; j < 8; ++j) {
            const float f = src[(size_t)(g * 8 + j) * MM + m_abs];
            const __bf16 hi = (__bf16)f;
            hh[j] = hi;
            ll[j] = (__bf16)(f - (float)hi);
        }
        const size_t o = (size_t)(b * MM + m_abs) * 64 + ((g ^ swz(m)) << 3);
        *reinterpret_cast<bf16x8*>(kt_hi + o) = hh;
        *reinterpret_cast<bf16x8*>(kt_lo + o) = ll;
    }
    for (int tsk = tid; tsk < 512; tsk += 256) {
        const int c = tsk & 63, gm = tsk >> 6;
        const float* p = src + (size_t)c * MM + t * 64 + gm * 8;
        bf16x8 hh;
        #pragma unroll
        for (int j = 0; j < 8; ++j) hh[j] = (__bf16)p[j];
        *reinterpret_cast<bf16x8*>(
            vt + (size_t)(b * CC + c) * MM + t * 64 + ((gm ^ swz(c)) << 3)) = hh;
    }
}

// ---------------- main flash kernel (32x32x16 fragments, log2-domain softmax) ----
template<bool FINAL>
__global__ __launch_bounds__(WAVES * 64, 2)
void attn_main(const __bf16* __restrict__ kt_hi, const __bf16* __restrict__ kt_lo,
               const __bf16* __restrict__ vt, const float* __restrict__ pi,
               float* __restrict__ out, float* __restrict__ opart,
               float* __restrict__ mlpart, const int nsplits)
{
    __shared__ __align__(16) __bf16 k_hi[MTILE][64];   // 8KB
    __shared__ __align__(16) __bf16 k_lo[MTILE][64];   // 8KB
    __shared__ __align__(16) __bf16 v_sm[CC][64];      // 8KB  -> 24KB total

    const int tid  = threadIdx.x;
    const int lane = tid & 63;
    const int wave = tid >> 6;     // 0..3
    const int l31  = lane & 31;
    const int hi   = lane >> 5;    // 0/1

    // ---- block decode: XCD-locality map when S==8 (1D grid), else plain 3D ----
    int bx, split, b;
    if (nsplits == 8 && gridDim.y == 1) {
        const int bid = blockIdx.x;           // 0..1151
        const int xcd = bid & 7, slot = bid >> 3;   // slot 0..143
        bx = slot % NBX;                      // n-block 0..71
        const int g = xcd + 8 * (slot / NBX); // group 0..15, all blocks on one XCD
        split = g & 7;
        b     = g >> 3;
    } else {
        bx = blockIdx.x; split = blockIdx.y; b = blockIdx.z;
    }

    const int tpb = NT / nsplits;
    const int t0s = split * tpb;
    const int n0  = bx * NBLK + wave * NPW;
    const int n_g = n0 + l31;

    // ---- async staging: 24 x 1KB chunks, 6 per wave, linear LDS dest ----
    auto stage = [&](int t) {
        const size_t kbase = (size_t)(b * MM + t * 64) * 64;   // elements
        #pragma unroll
        for (int q = 0; q < 6; ++q) {
            const int ch = wave * 6 + q;         // wave-uniform, 0..23
            if (ch < 8) {
                gld16(kt_hi + kbase + ch * 512 + lane * 8,
                      (char*)(&k_hi[0][0]) + ch * 1024);
            } else if (ch < 16) {
                const int j = ch - 8;
                gld16(kt_lo + kbase + j * 512 + lane * 8,
                      (char*)(&k_lo[0][0]) + j * 1024);
            } else {
                const int j = ch - 16;
                const int c = j * 8 + (lane >> 3);
                gld16(vt + (size_t)(b * CC + c) * MM + t * 64 + (lane & 7) * 8,
                      (char*)(&v_sm[0][0]) + j * 1024);
            }
        }
    };

    stage(t0s);   // DMA in flight while Q loads below

    // ---- Q fragments (hi/lo split), log2e folded in: s = log2e * (q.k) ----
    const float LOG2E = 1.4426950408889634f;
    bf16x8 qh[4], ql[4];
    {
        const float* qb = pi + (size_t)b * CC * MM + n_g;
        #pragma unroll
        for (int ks = 0; ks < 4; ++ks)
            #pragma unroll
            for (int j = 0; j < 8; ++j) {
                const float f = qb[(size_t)(ks * 16 + hi * 8 + j) * MM] * LOG2E;
                const __bf16 h = (__bf16)f;
                qh[ks][j] = h;
                ql[ks][j] = (__bf16)(f - (float)h);
            }
    }

    f32x16 o0, o1;
    #pragma unroll
    for (int r = 0; r < 16; ++r) { o0[r] = 0.f; o1[r] = 0.f; }
    float run_max = -INFINITY;   // log2-domain
    float run_l   = 0.f;

    const int sx0 = swz(l31) << 3;        // row swizzle, rows 0..31
    const int sx1 = swz(32 + l31) << 3;   // rows 32..63

    __syncthreads();   // vmcnt drained -> tile 0 ready

    for (int it = 0; it < tpb; ++it) {
        // ---- QK^T: S[m 64][n 32], split-bf16 (3 products) ----
        f32x16 s0, s1;
        #pragma unroll
        for (int r = 0; r < 16; ++r) { s0[r] = 0.f; s1[r] = 0.f; }
        __builtin_amdgcn_s_setprio(1);
        #pragma unroll
        for (int ks = 0; ks < 4; ++ks) {
            const int cb = ks * 16 + hi * 8;
            const bf16x8 ah0 = *(const bf16x8*)&k_hi[l31][cb ^ sx0];
            const bf16x8 al0 = *(const bf16x8*)&k_lo[l31][cb ^ sx0];
            const bf16x8 ah1 = *(const bf16x8*)&k_hi[32 + l31][cb ^ sx1];
            const bf16x8 al1 = *(const bf16x8*)&k_lo[32 + l31][cb ^ sx1];
            s0 = __builtin_amdgcn_mfma_f32_32x32x16_bf16(ah0, qh[ks], s0, 0, 0, 0);
            s1 = __builtin_amdgcn_mfma_f32_32x32x16_bf16(ah1, qh[ks], s1, 0, 0, 0);
            s0 = __builtin_amdgcn_mfma_f32_32x32x16_bf16(ah0, ql[ks], s0, 0, 0, 0);
            s1 = __builtin_amdgcn_mfma_f32_32x32x16_bf16(ah1, ql[ks], s1, 0, 0, 0);
            s0 = __builtin_amdgcn_mfma_f32_32x32x16_bf16(al0, qh[ks], s0, 0, 0, 0);
            s1 = __builtin_amdgcn_mfma_f32_32x32x16_bf16(al1, qh[ks], s1, 0, 0, 0);
        }
        __builtin_amdgcn_s_setprio(0);

        // ---- online softmax (log2-domain); rows of col n live in lanes {n, n+32} ----
        float t8[8];
        #pragma unroll
        for (int r = 0; r < 8; ++r)
            t8[r] = fmaxf(fmaxf(s0[r], s0[r + 8]), fmaxf(s1[r], s1[r + 8]));
        float tmax = fmaxf(fmaxf(fmaxf(t8[0], t8[1]), fmaxf(t8[2], t8[3])),
                           fmaxf(fmaxf(t8[4], t8[5]), fmaxf(t8[6], t8[7])));
        tmax = fmaxf(tmax, __shfl_xor(tmax, 32));   // R6-verified reduce

        if (!__all(tmax - run_max <= 11.09f)) {   // T13 defer (11.09 log2 == e^8)
            const float mnew = fmaxf(run_max, tmax);
            const float corr = fexp2(run_max - mnew);  // 0 on first iter
            run_l *= corr;
            #pragma unroll
            for (int r = 0; r < 16; ++r) { o0[r] *= corr; o1[r] *= corr; }
            run_max = mnew;
        }

        float ps[8];
        #pragma unroll
        for (int r = 0; r < 8; ++r) {
            s0[r]     = fexp2(s0[r]     - run_max);
            s0[r + 8] = fexp2(s0[r + 8] - run_max);
            s1[r]     = fexp2(s1[r]     - run_max);
            s1[r + 8] = fexp2(s1[r + 8] - run_max);
            ps[r] = (s0[r] + s0[r + 8]) + (s1[r] + s1[r + 8]);
        }
        float psum = ((ps[0] + ps[1]) + (ps[2] + ps[3])) +
                     ((ps[4] + ps[5]) + (ps[6] + ps[7]));
        psum += __shfl_xor(psum, 32);               // R6-verified reduce
        run_l += psum;

        // ---- pack P to bf16 dwords: X[mt][q][d] = pack(p[4q+2d], p[4q+2d+1]) ----
        unsigned int X[2][4][2];
        #pragma unroll
        for (int q = 0; q < 4; ++q)
            #pragma unroll
            for (int d = 0; d < 2; ++d) {
                X[0][q][d] = pack2(s0[4 * q + 2 * d], s0[4 * q + 2 * d + 1]);
                X[1][q][d] = pack2(s1[4 * q + 2 * d], s1[4 * q + 2 * d + 1]);
            }

        // ---- PV: B-frag via shfl_xor + selects (R6-verified exchange) ----
        __builtin_amdgcn_s_setprio(1);
        #pragma unroll
        for (int ks = 0; ks < 4; ++ks) {
            const int mt = ks >> 1, e = ks & 1;
            const unsigned int A0 = X[mt][2 * e][0],     A1 = X[mt][2 * e][1];
            const unsigned int B0 = X[mt][2 * e + 1][0], B1 = X[mt][2 * e + 1][1];
            // partner (hi=0 lane) needs my A-pair; partner (hi=1) needs my B-pair
            const unsigned int r0 = __shfl_xor(hi ? A0 : B0, 32);
            const unsigned int r1 = __shfl_xor(hi ? A1 : B1, 32);
            u32x4 w;
            w.x = hi ? r0 : A0;   // j=0..1
            w.y = hi ? r1 : A1;   // j=2..3
            w.z = hi ? B0 : r0;   // j=4..5
            w.w = hi ? B1 : r1;   // j=6..7
            const bf16x8 bp = __builtin_bit_cast(bf16x8, w);

            const int cb = ks * 16 + hi * 8;
            const bf16x8 av0 = *(const bf16x8*)&v_sm[l31][cb ^ sx0];
            const bf16x8 av1 = *(const bf16x8*)&v_sm[32 + l31][cb ^ sx1];
            o0 = __builtin_amdgcn_mfma_f32_32x32x16_bf16(av0, bp, o0, 0, 0, 0);
            o1 = __builtin_amdgcn_mfma_f32_32x32x16_bf16(av1, bp, o1, 0, 0, 0);
        }
        __builtin_amdgcn_s_setprio(0);

        __syncthreads();   // all waves done reading k/v -> safe to overwrite
        if (it + 1 < tpb) stage(t0s + it + 1);
        __syncthreads();   // vmcnt drained -> next tile visible
    }

    // ---- epilogue: c = (r&3) + 8*(r>>2) + 4*hi ----
    if (FINAL) {
        const float inv = 1.f / run_l;
        #pragma unroll
        for (int r = 0; r < 16; ++r) {
            const int cl = (r & 3) + 8 * (r >> 2) + 4 * hi;
            out[((size_t)b * CC + cl) * MM + n_g]      = o0[r] * inv;
            out[((size_t)b * CC + cl + 32) * MM + n_g] = o1[r] * inv;
        }
    } else {
        const size_t pbase = (size_t)(b * nsplits + split) * CC * MM;
        #pragma unroll
        for (int r = 0; r < 16; ++r) {
            const int cl = (r & 3) + 8 * (r >> 2) + 4 * hi;
            opart[pbase + (size_t)cl * MM + n_g]        = o0[r];
            opart[pbase + (size_t)(cl + 32) * MM + n_g] = o1[r];
        }
        if (hi == 0) {   // lanes n and n+32 hold identical (run_max, run_l)
            const size_t mb = ((size_t)(b * nsplits + split) * MM + n_g) * 2;
            mlpart[mb]     = run_max;   // log2-domain
            mlpart[mb + 1] = run_l;
        }
    }
}

// out = sum_s O_s * 2^{m_s - M} / sum_s l_s * 2^{m_s - M}  (4 n per thread)
template<int S>
__global__ __launch_bounds__(256)
void attn_reduce4(const float* __restrict__ opart, const float* __restrict__ mlpart,
                  float* __restrict__ out)
{
    const int t = blockIdx.x * 256 + threadIdx.x;
    if (t >= BB * CC * MM / 4) return;
    const int n  = (t * 4) % MM;
    const int bc = (t * 4) / MM;
    const int b  = bc / CC;
    const int c  = bc - b * CC;

    float wm[S][4], ls[S][4];
    float Mx[4] = {-INFINITY, -INFINITY, -INFINITY, -INFINITY};
    #pragma unroll
    for (int s = 0; s < S; ++s) {
        const float* mp = mlpart + ((size_t)(b * S + s) * MM + n) * 2;
        const float4 a = *reinterpret_cast<const float4*>(mp);
        const float4 q = *reinterpret_cast<const float4*>(mp + 4);
        wm[s][0] = a.x; ls[s][0] = a.y;
        wm[s][1] = a.z; ls[s][1] = a.w;
        wm[s][2] = q.x; ls[s][2] = q.y;
        wm[s][3] = q.z; ls[s][3] = q.w;
        #pragma unroll
        for (int j = 0; j < 4; ++j) Mx[j] = fmaxf(Mx[j], wm[s][j]);
    }
    float L[4] = {0.f, 0.f, 0.f, 0.f};
    #pragma unroll
    for (int s = 0; s < S; ++s)
        #pragma unroll
        for (int j = 0; j < 4; ++j) {
            wm[s][j] = fexp2(wm[s][j] - Mx[j]);   // log2-domain weights
            L[j] += ls[s][j] * wm[s][j];
        }
    float acc[4] = {0.f, 0.f, 0.f, 0.f};
    #pragma unroll
    for (int s = 0; s < S; ++s) {
        const float4 o4 = *reinterpret_cast<const float4*>(
            &opart[((size_t)(b * S + s) * CC + c) * MM + n]);
        acc[0] += o4.x * wm[s][0];
        acc[1] += o4.y * wm[s][1];
        acc[2] += o4.z * wm[s][2];
        acc[3] += o4.w * wm[s][3];
    }
    float4 r;
    r.x = acc[0] / L[0]; r.y = acc[1] / L[1];
    r.z = acc[2] / L[2]; r.w = acc[3] / L[3];
    *reinterpret_cast<float4*>(&out[(size_t)t * 4]) = r;
}

extern "C" void kernel_launch(void* const* d_in, const int* in_sizes, int n_in,
                              void* d_out, int out_size, void* d_ws, size_t ws_size,
                              hipStream_t stream) {
    const float* yi = (const float*)d_in[0];   // feature_yi (K = V)
    const float* pi = (const float*)d_in[1];   // feature_pi (Q)
    float* out = (float*)d_out;

    const size_t kelems = (size_t)BB * MM * 64;              // kt_hi / kt_lo elements
    const size_t velems = (size_t)BB * CC * MM;              // vt elements
    const size_t preB   = (kelems * 2 + velems) * 2;         // ~7.1 MB
    auto need = [&](int s) -> size_t {
        return preB + (size_t)BB * s * CC * MM * 4 + (size_t)BB * s * MM * 8;
    };

    int S = 1;
    if (d_ws) {
        if (ws_size >= need(8))      S = 8;
        else if (ws_size >= need(4)) S = 4;
        else if (ws_size >= need(2)) S = 2;
    }

    if (S == 1) {
        if (!d_ws || ws_size < preB) return;
        __bf16* kt_hi = (__bf16*)d_ws;
        __bf16* kt_lo = kt_hi + kelems;
        __bf16* vt    = kt_lo + kelems;
        prepass<<<dim3(NT, BB), dim3(256), 0, stream>>>(yi, kt_hi, kt_lo, vt);
        attn_main<true><<<dim3(NBX, 1, BB), dim3(WAVES * 64), 0, stream>>>(
            kt_hi, kt_lo, vt, pi, out, out, out, 1);
        return;
    }

    __bf16* kt_hi = (__bf16*)d_ws;
    __bf16* kt_lo = kt_hi + kelems;
    __bf16* vt    = kt_lo + kelems;
    float* opart  = (float*)(vt + velems);
    float* ml     = opart + (size_t)BB * S * CC * MM;

    prepass<<<dim3(NT, BB), dim3(256), 0, stream>>>(yi, kt_hi, kt_lo, vt);

    if (S == 8) {
        // 1D grid, XCD-locality mapping (all 72 n-blocks of a (b,split)
        // group land on one XCD; working set fits 4MB L2)
        attn_main<false><<<dim3(NBX * 8 * BB), dim3(WAVES * 64), 0, stream>>>(
            kt_hi, kt_lo, vt, pi, out, opart, ml, 8);
    } else {
        attn_main<false><<<dim3(NBX, S, BB), dim3(WAVES * 64), 0, stream>>>(
            kt_hi, kt_lo, vt, pi, out, opart, ml, S);
    }

    const int total4 = BB * CC * MM / 4;
    const dim3 rg((total4 + 255) / 256), rb(256);
    if (S == 8)      attn_reduce4<8><<<rg, rb, 0, stream>>>(opart, ml, out);
    else if (S == 4) attn_reduce4<4><<<rg, rb, 0, stream>>>(opart, ml, out);
    else             attn_reduce4<2><<<rg, rb, 0, stream>>>(opart, ml, out);
}